// Round 1
// baseline (2399.686 us; speedup 1.0000x reference)
//
#include <hip/hip_runtime.h>
#include <hip/hip_bf16.h>
#include <math.h>

#define BB 2
#define TT 2048
#define DD 768
#define HH 12
#define DHH 64
// M = BB*TT = 4096, K = N = 768 for the projections.

// ---------------------------------------------------------------------------
// 128x128x8 fp32 tiled GEMM for the QKV projections.
// C[m][n] = x[m][:] @ W[:][n] + bias[n], scattered to [B][H][T][DH] layout.
// grid = (M/128, N/128, 3), block = 256 (16x16 threads, 8x8 microtile each)
// ---------------------------------------------------------------------------
__global__ __launch_bounds__(256) void qkv_gemm(
    const float* __restrict__ x,
    const float* __restrict__ Wq, const float* __restrict__ bq,
    const float* __restrict__ Wk, const float* __restrict__ bk,
    const float* __restrict__ Wv, const float* __restrict__ bv,
    float* __restrict__ qo, float* __restrict__ ko, float* __restrict__ vo)
{
    const int which = blockIdx.z;
    const float* __restrict__ Wm   = (which == 0) ? Wq : (which == 1) ? Wk : Wv;
    const float* __restrict__ bias = (which == 0) ? bq : (which == 1) ? bk : bv;
    float* __restrict__ out        = (which == 0) ? qo : (which == 1) ? ko : vo;

    __shared__ float As[8][128];
    __shared__ float Bs[8][128];

    const int tid = threadIdx.x;
    const int tx = tid & 15, ty = tid >> 4;
    const int m0 = blockIdx.x * 128, n0 = blockIdx.y * 128;

    // A-tile load: 128 rows x 8 k = 1024 floats = 256 float4; 1 float4/thread
    const int ar = tid >> 1;            // row 0..127
    const int ak = (tid & 1) * 4;       // k 0 or 4
    // B-tile load: 8 k-rows x 128 cols; 1 float4/thread
    const int bkr = tid >> 5;           // k-row 0..7
    const int bn  = (tid & 31) * 4;     // col 0..124

    float acc[8][8];
    #pragma unroll
    for (int i = 0; i < 8; ++i)
        #pragma unroll
        for (int j = 0; j < 8; ++j) acc[i][j] = 0.f;

    #pragma unroll 1
    for (int k0 = 0; k0 < DD; k0 += 8) {
        const float4 av  = *(const float4*)&x [(size_t)(m0 + ar) * DD + k0 + ak];
        const float4 bv4 = *(const float4*)&Wm[(size_t)(k0 + bkr) * DD + n0 + bn];
        As[ak + 0][ar] = av.x;
        As[ak + 1][ar] = av.y;
        As[ak + 2][ar] = av.z;
        As[ak + 3][ar] = av.w;
        *(float4*)&Bs[bkr][bn] = bv4;
        __syncthreads();
        #pragma unroll
        for (int kk = 0; kk < 8; ++kk) {
            const float4 a0 = *(const float4*)&As[kk][ty * 8];
            const float4 a1 = *(const float4*)&As[kk][ty * 8 + 4];
            const float4 b0 = *(const float4*)&Bs[kk][tx * 8];
            const float4 b1 = *(const float4*)&Bs[kk][tx * 8 + 4];
            const float a[8] = {a0.x, a0.y, a0.z, a0.w, a1.x, a1.y, a1.z, a1.w};
            const float b[8] = {b0.x, b0.y, b0.z, b0.w, b1.x, b1.y, b1.z, b1.w};
            #pragma unroll
            for (int i = 0; i < 8; ++i)
                #pragma unroll
                for (int j = 0; j < 8; ++j)
                    acc[i][j] = fmaf(a[i], b[j], acc[i][j]);
        }
        __syncthreads();
    }

    // epilogue: scatter to [B][H][T][DH] (+bias). 8-col chunks stay within one head.
    const int nb = n0 + tx * 8;
    const int hh = nb >> 6, d0 = nb & 63;
    float brow[8];
    #pragma unroll
    for (int j = 0; j < 8; ++j) brow[j] = bias[nb + j];
    #pragma unroll
    for (int i = 0; i < 8; ++i) {
        const int m = m0 + ty * 8 + i;
        const int bb = m >> 11, t = m & 2047;
        float* dst = out + (((size_t)bb * HH + hh) * TT + t) * DHH + d0;
        float4 v0 = make_float4(acc[i][0] + brow[0], acc[i][1] + brow[1],
                                acc[i][2] + brow[2], acc[i][3] + brow[3]);
        float4 v1 = make_float4(acc[i][4] + brow[4], acc[i][5] + brow[5],
                                acc[i][6] + brow[6], acc[i][7] + brow[7]);
        *(float4*)&dst[0] = v0;
        *(float4*)&dst[4] = v1;
    }
}

// ---------------------------------------------------------------------------
// Output projection: out[m][n] = ctx[m][:] @ Wo[:][n] + bo[n], row-major out.
// ---------------------------------------------------------------------------
__global__ __launch_bounds__(256) void out_gemm(
    const float* __restrict__ ctx,
    const float* __restrict__ Wo, const float* __restrict__ bo,
    float* __restrict__ out)
{
    __shared__ float As[8][128];
    __shared__ float Bs[8][128];

    const int tid = threadIdx.x;
    const int tx = tid & 15, ty = tid >> 4;
    const int m0 = blockIdx.x * 128, n0 = blockIdx.y * 128;

    const int ar = tid >> 1;
    const int ak = (tid & 1) * 4;
    const int bkr = tid >> 5;
    const int bn  = (tid & 31) * 4;

    float acc[8][8];
    #pragma unroll
    for (int i = 0; i < 8; ++i)
        #pragma unroll
        for (int j = 0; j < 8; ++j) acc[i][j] = 0.f;

    #pragma unroll 1
    for (int k0 = 0; k0 < DD; k0 += 8) {
        const float4 av  = *(const float4*)&ctx[(size_t)(m0 + ar) * DD + k0 + ak];
        const float4 bv4 = *(const float4*)&Wo [(size_t)(k0 + bkr) * DD + n0 + bn];
        As[ak + 0][ar] = av.x;
        As[ak + 1][ar] = av.y;
        As[ak + 2][ar] = av.z;
        As[ak + 3][ar] = av.w;
        *(float4*)&Bs[bkr][bn] = bv4;
        __syncthreads();
        #pragma unroll
        for (int kk = 0; kk < 8; ++kk) {
            const float4 a0 = *(const float4*)&As[kk][ty * 8];
            const float4 a1 = *(const float4*)&As[kk][ty * 8 + 4];
            const float4 b0 = *(const float4*)&Bs[kk][tx * 8];
            const float4 b1 = *(const float4*)&Bs[kk][tx * 8 + 4];
            const float a[8] = {a0.x, a0.y, a0.z, a0.w, a1.x, a1.y, a1.z, a1.w};
            const float b[8] = {b0.x, b0.y, b0.z, b0.w, b1.x, b1.y, b1.z, b1.w};
            #pragma unroll
            for (int i = 0; i < 8; ++i)
                #pragma unroll
                for (int j = 0; j < 8; ++j)
                    acc[i][j] = fmaf(a[i], b[j], acc[i][j]);
        }
        __syncthreads();
    }

    const int nb = n0 + tx * 8;
    float brow[8];
    #pragma unroll
    for (int j = 0; j < 8; ++j) brow[j] = bo[nb + j];
    #pragma unroll
    for (int i = 0; i < 8; ++i) {
        const int m = m0 + ty * 8 + i;
        float* dst = out + (size_t)m * DD + nb;
        float4 v0 = make_float4(acc[i][0] + brow[0], acc[i][1] + brow[1],
                                acc[i][2] + brow[2], acc[i][3] + brow[3]);
        float4 v1 = make_float4(acc[i][4] + brow[4], acc[i][5] + brow[5],
                                acc[i][6] + brow[6], acc[i][7] + brow[7]);
        *(float4*)&dst[0] = v0;
        *(float4*)&dst[4] = v1;
    }
}

// ---------------------------------------------------------------------------
// Flash-style causal attention, fp32.
// 1 wave per block; each block owns 64 query rows of one (b,h).
// Each lane owns one q row (q and O accumulator in registers).
// K/V staged in LDS as 64x64 tiles. Online softmax in 16-col sub-phases.
// grid = (T/64, B*H), block = 64.
// ---------------------------------------------------------------------------
__global__ __launch_bounds__(64, 1) void attn_fwd(
    const float* __restrict__ qb, const float* __restrict__ kb,
    const float* __restrict__ vb, float* __restrict__ ctx)
{
    const int qt = blockIdx.x;        // q tile 0..31
    const int bh = blockIdx.y;        // 0..23
    const int b = bh / HH, h = bh - b * HH;
    const int lane = threadIdx.x;     // 0..63 = q row within tile

    __shared__ float Ks[64][64];
    __shared__ float Vs[64][64];

    // q row -> registers
    float4 q4[16];
    const float* qrow = qb + ((size_t)bh * TT + qt * 64 + lane) * DHH;
    #pragma unroll
    for (int i = 0; i < 16; ++i) q4[i] = *(const float4*)&qrow[i * 4];

    float4 o4[16];
    #pragma unroll
    for (int i = 0; i < 16; ++i) o4[i] = make_float4(0.f, 0.f, 0.f, 0.f);
    float mx = -INFINITY, l = 0.f;

    #pragma unroll 1
    for (int kt = 0; kt <= qt; ++kt) {
        const float* Kt = kb + ((size_t)bh * TT + kt * 64) * DHH;
        const float* Vt = vb + ((size_t)bh * TT + kt * 64) * DHH;
        __syncthreads();   // previous-tile reads done before overwrite
        #pragma unroll
        for (int i = 0; i < 16; ++i) {
            const int f = i * 64 + lane;            // float4 id 0..1023
            const int r = f >> 4, c4 = (f & 15) << 2;
            *(float4*)&Ks[r][c4] = *(const float4*)&Kt[r * DHH + c4];
            *(float4*)&Vs[r][c4] = *(const float4*)&Vt[r * DHH + c4];
        }
        __syncthreads();

        const bool diag = (kt == qt);
        #pragma unroll 1
        for (int jj = 0; jj < 4; ++jj) {
            float s16[16];
            float tmax = -INFINITY;
            #pragma unroll
            for (int i = 0; i < 16; ++i) {
                const int j = jj * 16 + i;
                float acc = 0.f;
                #pragma unroll
                for (int dd = 0; dd < 16; ++dd) {
                    const float4 k4 = *(const float4*)&Ks[j][dd * 4];
                    acc = fmaf(q4[dd].x, k4.x, acc);
                    acc = fmaf(q4[dd].y, k4.y, acc);
                    acc = fmaf(q4[dd].z, k4.z, acc);
                    acc = fmaf(q4[dd].w, k4.w, acc);
                }
                acc *= 0.125f;                       // 1/sqrt(64)
                if (diag && j > lane) acc = -INFINITY;
                s16[i] = acc;
                tmax = fmaxf(tmax, acc);
            }
            const float mnew = fmaxf(mx, tmax);
            const float sc = __expf(mx - mnew);      // 0 when mx==-inf
            l *= sc;
            #pragma unroll
            for (int d = 0; d < 16; ++d) {
                o4[d].x *= sc; o4[d].y *= sc; o4[d].z *= sc; o4[d].w *= sc;
            }
            #pragma unroll
            for (int i = 0; i < 16; ++i) {
                const int j = jj * 16 + i;
                const float p = __expf(s16[i] - mnew);   // 0 for masked
                l += p;
                #pragma unroll
                for (int d = 0; d < 16; ++d) {
                    const float4 v4 = *(const float4*)&Vs[j][d * 4];
                    o4[d].x = fmaf(p, v4.x, o4[d].x);
                    o4[d].y = fmaf(p, v4.y, o4[d].y);
                    o4[d].z = fmaf(p, v4.z, o4[d].z);
                    o4[d].w = fmaf(p, v4.w, o4[d].w);
                }
            }
            mx = mnew;
        }
    }

    const float inv = 1.f / l;
    float* dst = ctx + ((size_t)(b * TT + qt * 64 + lane)) * DD + h * DHH;
    #pragma unroll
    for (int d = 0; d < 16; ++d) {
        const float4 ov = make_float4(o4[d].x * inv, o4[d].y * inv,
                                      o4[d].z * inv, o4[d].w * inv);
        *(float4*)&dst[d * 4] = ov;
    }
}

extern "C" void kernel_launch(void* const* d_in, const int* in_sizes, int n_in,
                              void* d_out, int out_size, void* d_ws, size_t ws_size,
                              hipStream_t stream) {
    (void)in_sizes; (void)n_in; (void)out_size; (void)ws_size;
    const float* x  = (const float*)d_in[0];
    const float* Wq = (const float*)d_in[1];
    const float* bq = (const float*)d_in[2];
    const float* Wk = (const float*)d_in[3];
    const float* bk = (const float*)d_in[4];
    const float* Wv = (const float*)d_in[5];
    const float* bv = (const float*)d_in[6];
    const float* Wo = (const float*)d_in[7];
    const float* bo = (const float*)d_in[8];
    float* out = (float*)d_out;

    const size_t QKV = (size_t)BB * HH * TT * DHH;   // 3,145,728 floats
    float* qbuf = (float*)d_ws;
    float* kbuf = qbuf + QKV;
    float* vbuf = kbuf + QKV;
    float* ctx  = vbuf + QKV;

    dim3 g1(32, 6, 3), blk1(256);
    qkv_gemm<<<g1, blk1, 0, stream>>>(x, Wq, bq, Wk, bk, Wv, bv, qbuf, kbuf, vbuf);

    dim3 g2(32, 24), blk2(64);
    attn_fwd<<<g2, blk2, 0, stream>>>(qbuf, kbuf, vbuf, ctx);

    dim3 g3(32, 6), blk3(256);
    out_gemm<<<g3, blk3, 0, stream>>>(ctx, Wo, bo, out);
}

// Round 2
// 161.929 us; speedup vs baseline: 14.8194x; 14.8194x over previous
//
#include <hip/hip_runtime.h>
#include <hip/hip_bf16.h>
#include <math.h>

typedef unsigned short u16;
typedef __attribute__((ext_vector_type(8))) short short8v;   // 8 bf16 = 4 VGPR
typedef __attribute__((ext_vector_type(4))) float f32x4;

#define BB 2
#define TT 2048
#define DD 768
#define HH 12
#define DHH 64
#define MM 4096   // BB*TT

__device__ __forceinline__ u16 f2bf(float f) {
    union { float f; unsigned u; } v; v.f = f;
    unsigned r = v.u + 0x7fff + ((v.u >> 16) & 1);   // round-to-nearest-even
    return (u16)(r >> 16);
}

// ---------------------------------------------------------------------------
// x fp32 -> bf16, row-major. grid 3072 x 256, one float4/thread (exact cover).
// ---------------------------------------------------------------------------
__global__ __launch_bounds__(256) void convert_x(const float* __restrict__ x,
                                                 u16* __restrict__ xb) {
    const int i = blockIdx.x * 256 + threadIdx.x;     // float4 index
    const float4 v = ((const float4*)x)[i];
    union { u16 s[4]; uint2 u; } o;
    o.s[0] = f2bf(v.x); o.s[1] = f2bf(v.y); o.s[2] = f2bf(v.z); o.s[3] = f2bf(v.w);
    ((uint2*)xb)[i] = o.u;
}

// ---------------------------------------------------------------------------
// W [K][N] fp32 -> Wt [N][K] bf16 (B^T form for gemm_bt). 64x64 LDS tiles.
// grid (12,12,4): z selects matrix.
// ---------------------------------------------------------------------------
__global__ __launch_bounds__(256) void transpose_cvt(
    const float* __restrict__ W0, const float* __restrict__ W1,
    const float* __restrict__ W2, const float* __restrict__ W3,
    u16* __restrict__ T0, u16* __restrict__ T1,
    u16* __restrict__ T2, u16* __restrict__ T3)
{
    const int z = blockIdx.z;
    const float* __restrict__ W = (z == 0) ? W0 : (z == 1) ? W1 : (z == 2) ? W2 : W3;
    u16* __restrict__ T = (z == 0) ? T0 : (z == 1) ? T1 : (z == 2) ? T2 : T3;

    __shared__ float tile[64][65];
    const int k0 = blockIdx.x * 64, n0 = blockIdx.y * 64;
    const int t = threadIdx.x;
    const int rr = t >> 4, c4 = (t & 15) * 4;

    #pragma unroll
    for (int j = 0; j < 4; ++j) {
        const int r = rr + j * 16;
        const float4 v = *(const float4*)&W[(size_t)(k0 + r) * DD + n0 + c4];
        tile[r][c4 + 0] = v.x; tile[r][c4 + 1] = v.y;
        tile[r][c4 + 2] = v.z; tile[r][c4 + 3] = v.w;
    }
    __syncthreads();
    #pragma unroll
    for (int j = 0; j < 4; ++j) {
        const int r = rr + j * 16;            // n-local row of Wt
        union { u16 s[4]; uint2 u; } o;
        #pragma unroll
        for (int jj = 0; jj < 4; ++jj) o.s[jj] = f2bf(tile[c4 + jj][r]);
        *(uint2*)&T[(size_t)(n0 + r) * DD + k0 + c4] = o.u;
    }
}

// ---------------------------------------------------------------------------
// bf16 MFMA GEMM, B^T input (m97 structure, reg-staged, linear LDS).
// C[M=4096][N=768] = A[M][768] * W[768][N] (+bias), tile 128x128, BK=64,
// 4 waves (2x2), each wave 64x64 = 4x4 frags of 16x16x32.
// mode 0: Q -> bf16 [b][h][t][d]; mode 1: K same; mode 2: V -> bf16 [b][h][d][t]
// mode 3: fp32 row-major d_out.
// ---------------------------------------------------------------------------
__global__ __launch_bounds__(256) void gemm_bt(
    const u16* __restrict__ A,
    const u16* __restrict__ Bt0, const u16* __restrict__ Bt1, const u16* __restrict__ Bt2,
    const float* __restrict__ b0, const float* __restrict__ b1, const float* __restrict__ b2,
    u16* __restrict__ oQ, u16* __restrict__ oK, u16* __restrict__ oVt,
    float* __restrict__ oF, int mode_base)
{
    const int mode = mode_base + blockIdx.z;
    const u16* __restrict__ Bt = (mode == 1) ? Bt1 : (mode == 2) ? Bt2 : Bt0;
    const float* __restrict__ bias = (mode == 1) ? b1 : (mode == 2) ? b2 : b0;

    __shared__ __attribute__((aligned(16))) u16 As[128 * 64];
    __shared__ __attribute__((aligned(16))) u16 Bs[128 * 64];

    const int tid = threadIdx.x;
    const int lane = tid & 63, w = tid >> 6;
    const int wr = w >> 1, wc = w & 1;
    const int lr = lane >> 4, lc = lane & 15;
    const int m0 = blockIdx.x * 128, n0 = blockIdx.y * 128;

    f32x4 acc[4][4];
    #pragma unroll
    for (int m = 0; m < 4; ++m)
        #pragma unroll
        for (int n = 0; n < 4; ++n) acc[m][n] = (f32x4){0.f, 0.f, 0.f, 0.f};

    #pragma unroll 1
    for (int k0 = 0; k0 < DD; k0 += 64) {
        __syncthreads();
        #pragma unroll
        for (int i = 0; i < 4; ++i) {
            const int c = i * 256 + tid;           // 16B chunk id 0..1023
            const int r = c >> 3, kbyte = (c & 7) * 16;
            *(short8v*)((char*)As + r * 128 + kbyte) =
                *(const short8v*)((const char*)A + ((size_t)(m0 + r) * DD + k0) * 2 + kbyte);
            *(short8v*)((char*)Bs + r * 128 + kbyte) =
                *(const short8v*)((const char*)Bt + ((size_t)(n0 + r) * DD + k0) * 2 + kbyte);
        }
        __syncthreads();
        #pragma unroll
        for (int s = 0; s < 2; ++s) {
            short8v af[4], bf[4];
            #pragma unroll
            for (int m = 0; m < 4; ++m)
                af[m] = *(const short8v*)((const char*)As +
                         (wr * 64 + m * 16 + lc) * 128 + s * 64 + lr * 16);
            #pragma unroll
            for (int n = 0; n < 4; ++n)
                bf[n] = *(const short8v*)((const char*)Bs +
                         (wc * 64 + n * 16 + lc) * 128 + s * 64 + lr * 16);
            #pragma unroll
            for (int m = 0; m < 4; ++m)
                #pragma unroll
                for (int n = 0; n < 4; ++n)
                    acc[m][n] = __builtin_amdgcn_mfma_f32_16x16x32_bf16(
                        af[m], bf[n], acc[m][n], 0, 0, 0);
        }
    }

    // epilogue
    #pragma unroll
    for (int n = 0; n < 4; ++n) {
        const int ng = n0 + wc * 64 + n * 16 + lc;
        const float bv = bias[ng];
        #pragma unroll
        for (int m = 0; m < 4; ++m) {
            const int mg0 = m0 + wr * 64 + m * 16 + lr * 4;
            if (mode == 3) {
                #pragma unroll
                for (int r = 0; r < 4; ++r)
                    oF[(size_t)(mg0 + r) * DD + ng] = acc[m][n][r] + bv;
            } else if (mode == 2) {
                const int bb = mg0 >> 11, tp = mg0 & 2047;
                const int h = ng >> 6, d = ng & 63;
                union { u16 s[4]; uint2 u; } o;
                #pragma unroll
                for (int r = 0; r < 4; ++r) o.s[r] = f2bf(acc[m][n][r] + bv);
                *(uint2*)&oVt[((size_t)(bb * HH + h) * DHH + d) * TT + tp] = o.u;
            } else {
                u16* __restrict__ dst = (mode == 0) ? oQ : oK;
                #pragma unroll
                for (int r = 0; r < 4; ++r) {
                    const int mg = mg0 + r;
                    const int bb = mg >> 11, tp = mg & 2047;
                    const int h = ng >> 6, d = ng & 63;
                    dst[((size_t)(bb * HH + h) * TT + tp) * DHH + d] =
                        f2bf(acc[m][n][r] + bv);
                }
            }
        }
    }
}

// ---------------------------------------------------------------------------
// MFMA flash attention (causal). 4 waves/block, 64 q-rows/block, KVBLK=64.
// LDS (32KB): Qs[64][64] | Ks[64][64] | Vts[64][64] | P[4][16][64], all bf16,
// all XOR-swizzled (row-stride-128B tiles are 16-way bank conflicts otherwise).
// grid (32, 24), qt = 31 - bx (LPT order for the causal imbalance).
// ---------------------------------------------------------------------------
#define SWZ(r, kb) (((r) * 128) + ((kb) ^ (((r) & 7) << 4)))

__global__ __launch_bounds__(256) void attn_fwd(
    const u16* __restrict__ qb, const u16* __restrict__ kbf,
    const u16* __restrict__ vtb, u16* __restrict__ ctx)
{
    __shared__ __attribute__((aligned(16))) unsigned char smem[32768];
    // regions: Qs @0, Ks @8192, Vts @16384, P @24576 + w*2048

    const int qt = 31 - blockIdx.x;
    const int bh = blockIdx.y;
    const int b = bh / HH, h = bh - b * HH;
    const int tid = threadIdx.x, lane = tid & 63, w = tid >> 6;
    const int lr = lane >> 4, lc = lane & 15;

    // stage Q tile (swizzled), once
    {
        const char* src = (const char*)(qb + ((size_t)bh * TT + qt * 64) * DHH);
        #pragma unroll
        for (int j = 0; j < 2; ++j) {
            const int c = tid * 2 + j;             // 16B chunk 0..511
            const int r = c >> 3, kbyte = (c & 7) * 16;
            *(short8v*)(smem + SWZ(r, kbyte)) =
                *(const short8v*)(src + r * 128 + kbyte);
        }
    }
    __syncthreads();
    short8v aq[2];
    #pragma unroll
    for (int s = 0; s < 2; ++s)
        aq[s] = *(const short8v*)(smem + SWZ(w * 16 + lc, s * 64 + lr * 16));

    f32x4 accO[4];
    #pragma unroll
    for (int f = 0; f < 4; ++f) accO[f] = (f32x4){0.f, 0.f, 0.f, 0.f};
    float mreg[4] = {-INFINITY, -INFINITY, -INFINITY, -INFINITY};
    float lreg[4] = {0.f, 0.f, 0.f, 0.f};

    #pragma unroll 1
    for (int kt = 0; kt <= qt; ++kt) {
        __syncthreads();   // previous tile's reads complete
        {
            const char* ksrc = (const char*)(kbf + ((size_t)bh * TT + kt * 64) * DHH);
            const char* vsrc = (const char*)(vtb + (size_t)bh * DHH * TT + kt * 64);
            #pragma unroll
            for (int j = 0; j < 2; ++j) {
                const int c = tid * 2 + j;
                const int r = c >> 3, kbyte = (c & 7) * 16;
                *(short8v*)(smem + 8192 + SWZ(r, kbyte)) =
                    *(const short8v*)(ksrc + r * 128 + kbyte);
                *(short8v*)(smem + 16384 + SWZ(r, kbyte)) =
                    *(const short8v*)(vsrc + (size_t)r * TT * 2 + kbyte);
            }
        }
        __syncthreads();

        // S = Q K^T (scaled)
        f32x4 accS[4];
        #pragma unroll
        for (int f = 0; f < 4; ++f) accS[f] = (f32x4){0.f, 0.f, 0.f, 0.f};
        #pragma unroll
        for (int s = 0; s < 2; ++s) {
            #pragma unroll
            for (int f = 0; f < 4; ++f) {
                const short8v bk = *(const short8v*)(smem + 8192 +
                                   SWZ(f * 16 + lc, s * 64 + lr * 16));
                accS[f] = __builtin_amdgcn_mfma_f32_16x16x32_bf16(aq[s], bk, accS[f], 0, 0, 0);
            }
        }
        const bool diag = (kt == qt);
        #pragma unroll
        for (int f = 0; f < 4; ++f)
            #pragma unroll
            for (int r = 0; r < 4; ++r) {
                float v = accS[f][r] * 0.125f;
                if (diag && (f * 16 + lc) > (w * 16 + lr * 4 + r)) v = -INFINITY;
                accS[f][r] = v;
            }

        // online softmax (row = lane's 4 regs; cols spread over 16-lane group)
        float pv[4][4];
        #pragma unroll
        for (int r = 0; r < 4; ++r) {
            float tm = fmaxf(fmaxf(accS[0][r], accS[1][r]),
                             fmaxf(accS[2][r], accS[3][r]));
            tm = fmaxf(tm, __shfl_xor(tm, 1));
            tm = fmaxf(tm, __shfl_xor(tm, 2));
            tm = fmaxf(tm, __shfl_xor(tm, 4));
            tm = fmaxf(tm, __shfl_xor(tm, 8));
            const float mnew = fmaxf(mreg[r], tm);
            const float sc = __expf(mreg[r] - mnew);
            mreg[r] = mnew;
            float rs = 0.f;
            #pragma unroll
            for (int f = 0; f < 4; ++f) {
                const float p = __expf(accS[f][r] - mnew);
                pv[f][r] = p;
                rs += p;
            }
            rs += __shfl_xor(rs, 1);
            rs += __shfl_xor(rs, 2);
            rs += __shfl_xor(rs, 4);
            rs += __shfl_xor(rs, 8);
            lreg[r] = lreg[r] * sc + rs;
            #pragma unroll
            for (int f = 0; f < 4; ++f) accO[f][r] *= sc;
        }

        // P -> wave-private LDS (bf16, swizzled), then read back as A-frags
        unsigned char* Pw = smem + 24576 + w * 2048;
        #pragma unroll
        for (int f = 0; f < 4; ++f)
            #pragma unroll
            for (int r = 0; r < 4; ++r) {
                const int rr = lr * 4 + r, cc = f * 16 + lc;
                *(u16*)(Pw + SWZ(rr, cc * 2)) = f2bf(pv[f][r]);
            }
        short8v ap[2];
        #pragma unroll
        for (int s = 0; s < 2; ++s)
            ap[s] = *(const short8v*)(Pw + SWZ(lc, s * 64 + lr * 16));

        // O += P V
        #pragma unroll
        for (int s = 0; s < 2; ++s)
            #pragma unroll
            for (int f = 0; f < 4; ++f) {
                const short8v bv = *(const short8v*)(smem + 16384 +
                                   SWZ(f * 16 + lc, s * 64 + lr * 16));
                accO[f] = __builtin_amdgcn_mfma_f32_16x16x32_bf16(ap[s], bv, accO[f], 0, 0, 0);
            }
    }

    // epilogue: normalize, write ctx bf16 row-major [b*t][768]
    #pragma unroll
    for (int r = 0; r < 4; ++r) lreg[r] = 1.f / lreg[r];
    const int qpos = qt * 64 + w * 16 + lr * 4;
    #pragma unroll
    for (int f = 0; f < 4; ++f) {
        const int col = h * 64 + f * 16 + lc;
        #pragma unroll
        for (int r = 0; r < 4; ++r)
            ctx[(size_t)(b * TT + qpos + r) * DD + col] = f2bf(accO[f][r] * lreg[r]);
    }
}

extern "C" void kernel_launch(void* const* d_in, const int* in_sizes, int n_in,
                              void* d_out, int out_size, void* d_ws, size_t ws_size,
                              hipStream_t stream) {
    (void)in_sizes; (void)n_in; (void)out_size; (void)ws_size;
    const float* x  = (const float*)d_in[0];
    const float* Wq = (const float*)d_in[1];
    const float* bq = (const float*)d_in[2];
    const float* Wk = (const float*)d_in[3];
    const float* bk = (const float*)d_in[4];
    const float* Wv = (const float*)d_in[5];
    const float* bv = (const float*)d_in[6];
    const float* Wo = (const float*)d_in[7];
    const float* bo = (const float*)d_in[8];
    float* out = (float*)d_out;

    u16* xb    = (u16*)d_ws;          // 4096*768
    u16* WtQ   = xb + (size_t)MM * DD;
    u16* WtK   = WtQ + (size_t)DD * DD;
    u16* WtV   = WtK + (size_t)DD * DD;
    u16* WtO   = WtV + (size_t)DD * DD;
    u16* qbuf  = WtO + (size_t)DD * DD;      // [b][h][t][d]
    u16* kbuf  = qbuf + (size_t)MM * DD;
    u16* vtbuf = kbuf + (size_t)MM * DD;     // [b][h][d][t]
    u16* ctxb  = vtbuf + (size_t)MM * DD;    // [b*t][768]

    convert_x<<<3072, 256, 0, stream>>>(x, xb);
    transpose_cvt<<<dim3(12, 12, 4), 256, 0, stream>>>(Wq, Wk, Wv, Wo, WtQ, WtK, WtV, WtO);
    gemm_bt<<<dim3(32, 6, 3), 256, 0, stream>>>(xb, WtQ, WtK, WtV, bq, bk, bv,
                                                qbuf, kbuf, vtbuf, nullptr, 0);
    attn_fwd<<<dim3(32, 24), 256, 0, stream>>>(qbuf, kbuf, vtbuf, ctxb);
    gemm_bt<<<dim3(32, 6, 1), 256, 0, stream>>>(ctxb, WtO, nullptr, nullptr, bo, nullptr, nullptr,
                                                nullptr, nullptr, nullptr, out, 3);
}